// Round 5
// baseline (76.279 us; speedup 1.0000x reference)
//
#include <hip/hip_runtime.h>

typedef unsigned short u16;
typedef short bf16x8 __attribute__((ext_vector_type(8)));
typedef u16 u16x8 __attribute__((ext_vector_type(8)));
typedef float f32x4 __attribute__((ext_vector_type(4)));

#define K_DIM 256
#define L_DIM 4096
#define NBATCH 4

static __device__ __forceinline__ u16 f2bf(float f) {
    unsigned u = __float_as_uint(f);
    unsigned r = (u + 0x7FFFu + ((u >> 16) & 1u)) >> 16;
    return (u16)r;
}
static __device__ __forceinline__ float bf2f(u16 v) {
    return __uint_as_float(((unsigned)v) << 16);
}

#define GLOAD16(g, l) __builtin_amdgcn_global_load_lds( \
    (const __attribute__((address_space(1))) void*)(g), \
    (__attribute__((address_space(3))) void*)(l), 16, 0, 0)

// ---------------------------------------------------------------------------
// K1: depthwise 3x3 conv + transpose + bf16 cast; weight casts folded in as
// extra blocks (blockIdx.x == 4).   [unchanged from round 3]
// ---------------------------------------------------------------------------
__global__ __launch_bounds__(256) void prep_kernel(
    const float* __restrict__ x, const float* __restrict__ dw_w,
    const float* __restrict__ dw_b, const float* __restrict__ pin_w,
    const float* __restrict__ pw_w, const float* __restrict__ pout_w,
    u16* __restrict__ xb_t, u16* __restrict__ dwc_t,
    u16* __restrict__ pin_wb, u16* __restrict__ pw_wb,
    u16* __restrict__ pout_wb)
{
    if (blockIdx.x == 4) {                      // weight-cast blocks
        if (blockIdx.z != 0) return;
        const int end = (blockIdx.y + 1) * 2560;
        for (int k = blockIdx.y * 2560 + threadIdx.x; k < end; k += 256) {
            if (k < 65536) pin_wb[k] = f2bf(pin_w[k]);
            else if (k < 98304) {
                int j = k - 65536;
                pw_wb[j] = ((j >> 8) < 112) ? f2bf(pw_w[j]) : (u16)0;
            } else {
                int j = k - 98304;
                pout_wb[j] = f2bf(pout_w[j]);
            }
        }
        return;
    }

    __shared__ u16 tx_[64][66];
    __shared__ u16 td_[64][66];
    const int c0 = blockIdx.x * 64, h = blockIdx.y, n = blockIdx.z;
    const int t = threadIdx.x, w = t & 63, cq = t >> 6;
    const float* xn = x + (size_t)n * 256 * L_DIM;
    const int wm = (w > 0) ? w - 1 : 0;
    const int wp = (w < 63) ? w + 1 : 63;
    const float lv = (w > 0) ? 1.f : 0.f;
    const float rv = (w < 63) ? 1.f : 0.f;

    for (int i = 0; i < 16; ++i) {
        const int cl = i * 4 + cq, c = c0 + cl;
        const float* xc = xn + (size_t)c * L_DIM;
        const float* w9 = dw_w + c * 9;
        float s = dw_b[c];
        #pragma unroll
        for (int dy = 0; dy < 3; ++dy) {
            const int hh = h + dy - 1;
            if (hh < 0 || hh > 63) continue;   // block-uniform branch
            const float* row = xc + hh * 64;
            s = fmaf(row[wm] * lv, w9[dy*3 + 0], s);
            s = fmaf(row[w],       w9[dy*3 + 1], s);
            s = fmaf(row[wp] * rv, w9[dy*3 + 2], s);
        }
        tx_[w][cl] = f2bf(xc[h*64 + w]);
        td_[w][cl] = f2bf(s);
    }
    __syncthreads();
    const int cc = t & 63;
    for (int j = 0; j < 16; ++j) {
        const int wl = j * 4 + cq;
        const size_t o = ((size_t)n * L_DIM + h * 64 + wl) * 256 + c0 + cc;
        xb_t[o]  = tx_[wl][cc];
        dwc_t[o] = td_[wl][cc];
    }
}

// ---------------------------------------------------------------------------
// K2: pin + pw GEMMs in one dispatch.   [unchanged from round 3]
// ---------------------------------------------------------------------------
__global__ __launch_bounds__(256) void gemm_dual(
    const u16* __restrict__ xb_t, const u16* __restrict__ dwc_t,
    const u16* __restrict__ pin_wb, const u16* __restrict__ pw_wb,
    const float* __restrict__ pin_b, const float* __restrict__ pw_b,
    u16* __restrict__ val_b, float* __restrict__ omb)
{
    __shared__ u16 lds[16384];
    const int bx = blockIdx.x;
    const bool isPw = (bx == 2);
    const u16* Ag = isPw ? dwc_t : xb_t;
    const u16* Bg = isPw ? pw_wb : pin_wb;
    const float* bias = isPw ? pw_b : pin_b;
    const int n0 = isPw ? 0 : bx * 128;
    const int Ncols = isPw ? 112 : 256;
    const int ldC = isPw ? 112 : 256;
    const int m0 = blockIdx.y * 128;

    const int t = threadIdx.x;
    const int wave = t >> 6, lane = t & 63;
    const int lr = lane & 15, lk = lane >> 4;
    const int wr = wave >> 1, wc = wave & 1;
    const int wbase = wave << 10;

    const int srow = t >> 2;
    const int scol = (t & 3) * 8;
    const u16* ga0 = Ag + (size_t)(m0 + srow)      * K_DIM + scol;
    const u16* ga1 = Ag + (size_t)(m0 + 64 + srow) * K_DIM + scol;
    const u16* gb0 = Bg + (size_t)(n0 + srow)      * K_DIM + scol;
    const u16* gb1 = Bg + (size_t)(n0 + 64 + srow) * K_DIM + scol;

    f32x4 acc[4][4];
    #pragma unroll
    for (int m = 0; m < 4; ++m)
        #pragma unroll
        for (int n = 0; n < 4; ++n) acc[m][n] = (f32x4){0.f, 0.f, 0.f, 0.f};

    auto stage = [&](int b, int kt) {
        const int ko = kt * 32;
        char* base = (char*)lds + b * 16384 + wbase;
        GLOAD16(ga0 + ko, base);
        GLOAD16(ga1 + ko, base + 4096);
        GLOAD16(gb0 + ko, base + 8192);
        GLOAD16(gb1 + ko, base + 12288);
    };

    stage(0, 0);
    asm volatile("s_waitcnt vmcnt(0)" ::: "memory");
    __syncthreads();

    for (int kt = 0; kt < 8; ++kt) {
        const int cur = kt & 1;
        if (kt < 7) stage(cur ^ 1, kt + 1);
        const char* la = (const char*)lds + cur * 16384;
        const char* lb = la + 8192;
        bf16x8 af[4], bfr[4];
        #pragma unroll
        for (int m = 0; m < 4; ++m)
            af[m] = *(const bf16x8*)(la + ((wr*64 + m*16 + lr) * 32 + lk * 8) * 2);
        #pragma unroll
        for (int n = 0; n < 4; ++n)
            bfr[n] = *(const bf16x8*)(lb + ((wc*64 + n*16 + lr) * 32 + lk * 8) * 2);
        #pragma unroll
        for (int m = 0; m < 4; ++m)
            #pragma unroll
            for (int n = 0; n < 4; ++n)
                acc[m][n] = __builtin_amdgcn_mfma_f32_16x16x32_bf16(
                    af[m], bfr[n], acc[m][n], 0, 0, 0);
        asm volatile("s_waitcnt vmcnt(0)" ::: "memory");
        __syncthreads();
    }

    #pragma unroll
    for (int m = 0; m < 4; ++m) {
        #pragma unroll
        for (int n = 0; n < 4; ++n) {
            const int col = n0 + wc*64 + n*16 + lr;
            if (col < Ncols) {
                const float bv = bias[col];
                #pragma unroll
                for (int r = 0; r < 4; ++r) {
                    const int row = m0 + wr*64 + m*16 + lk*4 + r;
                    const float o = acc[m][n][r] + bv;
                    const size_t off = (size_t)row * ldC + col;
                    if (isPw) omb[off] = o;
                    else      val_b[off] = f2bf(o);
                }
            }
        }
    }
}

// ---------------------------------------------------------------------------
// K3: fused deformable gather + output projection, high-occupancy version.
// Grid 1024 x 256 thr, 4 blocks/CU.  Block = (n, h, quarter-row) = 16 pos.
// XCD-octile decode: h = (blk&7)*8 + r so each XCD's val footprint (~1.6MB)
// stays L2-resident.  Wave = one group g; lane = (pos 0..15) x (16 ch).
// Then pout: 256c x 16pos tile, wave g covers c rows g*64..g*64+63.
// ---------------------------------------------------------------------------
__global__ __launch_bounds__(256, 4) void gather_pout(
    const float* __restrict__ om, const u16* __restrict__ val,
    const u16* __restrict__ pout_wb, const float* __restrict__ pout_b,
    float* __restrict__ out)
{
    __shared__ u16 sacc[16][264];
    const int blk = blockIdx.x;
    const int xcd = blk & 7, s = blk >> 3;        // s: 0..127
    const int qd = s & 3, rd = (s >> 2) & 7, n = s >> 5;
    const int h = xcd * 8 + rd;
    const int l0 = h * 64 + qd * 16;
    const int t = threadIdx.x;
    const int g = t >> 6, lane = t & 63;
    const int pos = lane >> 2;                     // 0..15
    const int chl = (lane & 3) * 16;               // channel base within group
    const int l = l0 + pos;

    const u16* valn = val + (size_t)n * L_DIM * 256;
    const u16* vb = valn + g * 64 + chl;
    const float* omp = om + ((size_t)n * L_DIM + l) * 112 + g * 27;
    const float yb = (float)h - 1.f;
    const float xb = (float)(l & 63) - 1.f;

    float a[16];
    #pragma unroll
    for (int j = 0; j < 16; ++j) a[j] = 0.f;

    #pragma unroll 3
    for (int p = 0; p < 9; ++p) {
        const float ox = omp[p*3 + 0];
        const float oy = omp[p*3 + 1];
        const float mk = omp[p*3 + 2];
        const float py = yb + (float)(p / 3) + oy;
        const float px = xb + (float)(p % 3) + ox;
        const float y0 = floorf(py), x0 = floorf(px);
        const float fy = py - y0, fx = px - x0;
        const int iy0 = (int)y0, ix0 = (int)x0;
        const float wy[2] = {mk * (1.f - fy), mk * fy};
        const float wx[2] = {1.f - fx, fx};
        #pragma unroll
        for (int c4 = 0; c4 < 4; ++c4) {
            const int dy = c4 >> 1, dx = c4 & 1;
            const int iy = iy0 + dy, ix = ix0 + dx;
            const bool ok = ((unsigned)iy < 64u) & ((unsigned)ix < 64u);
            const float wgt = ok ? wy[dy] * wx[dx] : 0.f;
            const int iyc = min(max(iy, 0), 63);
            const int ixc = min(max(ix, 0), 63);
            const u16* lp = vb + (size_t)(iyc * 64 + ixc) * 256;
            const u16x8 v0 = *(const u16x8*)lp;
            const u16x8 v1 = *(const u16x8*)(lp + 8);
            #pragma unroll
            for (int j = 0; j < 8; ++j) a[j]     = fmaf(wgt, bf2f(v0[j]), a[j]);
            #pragma unroll
            for (int j = 0; j < 8; ++j) a[j + 8] = fmaf(wgt, bf2f(v1[j]), a[j + 8]);
        }
    }
    u16x8 o0, o1;
    #pragma unroll
    for (int j = 0; j < 8; ++j) { o0[j] = f2bf(a[j]); o1[j] = f2bf(a[j + 8]); }
    *(u16x8*)(&sacc[pos][g*64 + chl])     = o0;
    *(u16x8*)(&sacc[pos][g*64 + chl + 8]) = o1;
    __syncthreads();

    // ---- pout: C[c, pos] = sum_k pout_w[c,k] * sacc[pos,k], c-rows per wave ----
    const int lr = lane & 15, lk = lane >> 4;

    f32x4 acc4[4];
    #pragma unroll
    for (int m = 0; m < 4; ++m) acc4[m] = (f32x4){0.f, 0.f, 0.f, 0.f};

    #pragma unroll
    for (int kt = 0; kt < 8; ++kt) {
        const bf16x8 bf = *(const bf16x8*)(&sacc[lr][kt*32 + lk*8]);
        #pragma unroll
        for (int m = 0; m < 4; ++m) {
            const bf16x8 af = *(const bf16x8*)(pout_wb +
                (size_t)(g*64 + m*16 + lr) * K_DIM + kt*32 + lk*8);
            acc4[m] = __builtin_amdgcn_mfma_f32_16x16x32_bf16(af, bf, acc4[m], 0, 0, 0);
        }
    }

    float* outn = out + (size_t)n * 256 * L_DIM;
    #pragma unroll
    for (int m = 0; m < 4; ++m) {
        #pragma unroll
        for (int r = 0; r < 4; ++r) {
            const int row = g*64 + m*16 + lk*4 + r;
            outn[(size_t)row * L_DIM + l0 + lr] = acc4[m][r] + pout_b[row];
        }
    }
}

// ---------------------------------------------------------------------------
extern "C" void kernel_launch(void* const* d_in, const int* in_sizes, int n_in,
                              void* d_out, int out_size, void* d_ws, size_t ws_size,
                              hipStream_t stream) {
    const float* x      = (const float*)d_in[0];
    const float* dw_w   = (const float*)d_in[1];
    const float* dw_b   = (const float*)d_in[2];
    const float* pw_w   = (const float*)d_in[3];
    const float* pw_b   = (const float*)d_in[4];
    const float* pin_w  = (const float*)d_in[5];
    const float* pin_b  = (const float*)d_in[6];
    const float* pout_w = (const float*)d_in[7];
    const float* pout_b = (const float*)d_in[8];
    float* out = (float*)d_out;

    char* ws = (char*)d_ws;
    u16*   xb_t    = (u16*)ws;                      //  8,388,608
    u16*   dwc_t   = (u16*)(ws + 8388608);          //  8,388,608
    u16*   val_b   = (u16*)(ws + 16777216);         //  8,388,608
    float* omb     = (float*)(ws + 25165824);       //  7,340,032
    u16*   pin_wb  = (u16*)(ws + 32505856);         //    131,072
    u16*   pw_wb   = (u16*)(ws + 32636928);         //     65,536 (128 rows)
    u16*   pout_wb = (u16*)(ws + 32702464);         //    131,072

    // K1: depthwise conv + transpose-cast + weight casts
    prep_kernel<<<dim3(5, 64, NBATCH), 256, 0, stream>>>(
        x, dw_w, dw_b, pin_w, pw_w, pout_w,
        xb_t, dwc_t, pin_wb, pw_wb, pout_wb);

    // K2: val = pin(x) [bf16], om = pw(dwc) [fp32]
    gemm_dual<<<dim3(3, 128), 256, 0, stream>>>(
        xb_t, dwc_t, pin_wb, pw_wb, pin_b, pw_b, val_b, omb);

    // K3: deformable gather + pout projection, 4 blocks/CU
    gather_pout<<<dim3(1024), 256, 0, stream>>>(
        omb, val_b, pout_wb, pout_b, out);
}

// Round 6
// 73.845 us; speedup vs baseline: 1.0330x; 1.0330x over previous
//
#include <hip/hip_runtime.h>

typedef unsigned short u16;
typedef short bf16x8 __attribute__((ext_vector_type(8)));
typedef u16 u16x8 __attribute__((ext_vector_type(8)));
typedef float f32x4 __attribute__((ext_vector_type(4)));

#define K_DIM 256
#define L_DIM 4096
#define NBATCH 4

static __device__ __forceinline__ u16 f2bf(float f) {
    unsigned u = __float_as_uint(f);
    unsigned r = (u + 0x7FFFu + ((u >> 16) & 1u)) >> 16;
    return (u16)r;
}
static __device__ __forceinline__ float bf2f(u16 v) {
    return __uint_as_float(((unsigned)v) << 16);
}

#define GLOAD16(g, l) __builtin_amdgcn_global_load_lds( \
    (const __attribute__((address_space(1))) void*)(g), \
    (__attribute__((address_space(3))) void*)(l), 16, 0, 0)

// ---------------------------------------------------------------------------
// K1: depthwise 3x3 conv + transpose + bf16 cast; weight casts folded in as
// extra blocks (blockIdx.x == 4).   [unchanged]
// ---------------------------------------------------------------------------
__global__ __launch_bounds__(256) void prep_kernel(
    const float* __restrict__ x, const float* __restrict__ dw_w,
    const float* __restrict__ dw_b, const float* __restrict__ pin_w,
    const float* __restrict__ pw_w, const float* __restrict__ pout_w,
    u16* __restrict__ xb_t, u16* __restrict__ dwc_t,
    u16* __restrict__ pin_wb, u16* __restrict__ pw_wb,
    u16* __restrict__ pout_wb)
{
    if (blockIdx.x == 4) {                      // weight-cast blocks
        if (blockIdx.z != 0) return;
        const int end = (blockIdx.y + 1) * 2560;
        for (int k = blockIdx.y * 2560 + threadIdx.x; k < end; k += 256) {
            if (k < 65536) pin_wb[k] = f2bf(pin_w[k]);
            else if (k < 98304) {
                int j = k - 65536;
                pw_wb[j] = ((j >> 8) < 112) ? f2bf(pw_w[j]) : (u16)0;
            } else {
                int j = k - 98304;
                pout_wb[j] = f2bf(pout_w[j]);
            }
        }
        return;
    }

    __shared__ u16 tx_[64][66];
    __shared__ u16 td_[64][66];
    const int c0 = blockIdx.x * 64, h = blockIdx.y, n = blockIdx.z;
    const int t = threadIdx.x, w = t & 63, cq = t >> 6;
    const float* xn = x + (size_t)n * 256 * L_DIM;
    const int wm = (w > 0) ? w - 1 : 0;
    const int wp = (w < 63) ? w + 1 : 63;
    const float lv = (w > 0) ? 1.f : 0.f;
    const float rv = (w < 63) ? 1.f : 0.f;

    for (int i = 0; i < 16; ++i) {
        const int cl = i * 4 + cq, c = c0 + cl;
        const float* xc = xn + (size_t)c * L_DIM;
        const float* w9 = dw_w + c * 9;
        float s = dw_b[c];
        #pragma unroll
        for (int dy = 0; dy < 3; ++dy) {
            const int hh = h + dy - 1;
            if (hh < 0 || hh > 63) continue;   // block-uniform branch
            const float* row = xc + hh * 64;
            s = fmaf(row[wm] * lv, w9[dy*3 + 0], s);
            s = fmaf(row[w],       w9[dy*3 + 1], s);
            s = fmaf(row[wp] * rv, w9[dy*3 + 2], s);
        }
        tx_[w][cl] = f2bf(xc[h*64 + w]);
        td_[w][cl] = f2bf(s);
    }
    __syncthreads();
    const int cc = t & 63;
    for (int j = 0; j < 16; ++j) {
        const int wl = j * 4 + cq;
        const size_t o = ((size_t)n * L_DIM + h * 64 + wl) * 256 + c0 + cc;
        xb_t[o]  = tx_[wl][cc];
        dwc_t[o] = td_[wl][cc];
    }
}

// ---------------------------------------------------------------------------
// K2: pin + pw GEMMs in one dispatch.   [unchanged]
// ---------------------------------------------------------------------------
__global__ __launch_bounds__(256) void gemm_dual(
    const u16* __restrict__ xb_t, const u16* __restrict__ dwc_t,
    const u16* __restrict__ pin_wb, const u16* __restrict__ pw_wb,
    const float* __restrict__ pin_b, const float* __restrict__ pw_b,
    u16* __restrict__ val_b, float* __restrict__ omb)
{
    __shared__ u16 lds[16384];
    const int bx = blockIdx.x;
    const bool isPw = (bx == 2);
    const u16* Ag = isPw ? dwc_t : xb_t;
    const u16* Bg = isPw ? pw_wb : pin_wb;
    const float* bias = isPw ? pw_b : pin_b;
    const int n0 = isPw ? 0 : bx * 128;
    const int Ncols = isPw ? 112 : 256;
    const int ldC = isPw ? 112 : 256;
    const int m0 = blockIdx.y * 128;

    const int t = threadIdx.x;
    const int wave = t >> 6, lane = t & 63;
    const int lr = lane & 15, lk = lane >> 4;
    const int wr = wave >> 1, wc = wave & 1;
    const int wbase = wave << 10;

    const int srow = t >> 2;
    const int scol = (t & 3) * 8;
    const u16* ga0 = Ag + (size_t)(m0 + srow)      * K_DIM + scol;
    const u16* ga1 = Ag + (size_t)(m0 + 64 + srow) * K_DIM + scol;
    const u16* gb0 = Bg + (size_t)(n0 + srow)      * K_DIM + scol;
    const u16* gb1 = Bg + (size_t)(n0 + 64 + srow) * K_DIM + scol;

    f32x4 acc[4][4];
    #pragma unroll
    for (int m = 0; m < 4; ++m)
        #pragma unroll
        for (int n = 0; n < 4; ++n) acc[m][n] = (f32x4){0.f, 0.f, 0.f, 0.f};

    auto stage = [&](int b, int kt) {
        const int ko = kt * 32;
        char* base = (char*)lds + b * 16384 + wbase;
        GLOAD16(ga0 + ko, base);
        GLOAD16(ga1 + ko, base + 4096);
        GLOAD16(gb0 + ko, base + 8192);
        GLOAD16(gb1 + ko, base + 12288);
    };

    stage(0, 0);
    asm volatile("s_waitcnt vmcnt(0)" ::: "memory");
    __syncthreads();

    for (int kt = 0; kt < 8; ++kt) {
        const int cur = kt & 1;
        if (kt < 7) stage(cur ^ 1, kt + 1);
        const char* la = (const char*)lds + cur * 16384;
        const char* lb = la + 8192;
        bf16x8 af[4], bfr[4];
        #pragma unroll
        for (int m = 0; m < 4; ++m)
            af[m] = *(const bf16x8*)(la + ((wr*64 + m*16 + lr) * 32 + lk * 8) * 2);
        #pragma unroll
        for (int n = 0; n < 4; ++n)
            bfr[n] = *(const bf16x8*)(lb + ((wc*64 + n*16 + lr) * 32 + lk * 8) * 2);
        #pragma unroll
        for (int m = 0; m < 4; ++m)
            #pragma unroll
            for (int n = 0; n < 4; ++n)
                acc[m][n] = __builtin_amdgcn_mfma_f32_16x16x32_bf16(
                    af[m], bfr[n], acc[m][n], 0, 0, 0);
        asm volatile("s_waitcnt vmcnt(0)" ::: "memory");
        __syncthreads();
    }

    #pragma unroll
    for (int m = 0; m < 4; ++m) {
        #pragma unroll
        for (int n = 0; n < 4; ++n) {
            const int col = n0 + wc*64 + n*16 + lr;
            if (col < Ncols) {
                const float bv = bias[col];
                #pragma unroll
                for (int r = 0; r < 4; ++r) {
                    const int row = m0 + wr*64 + m*16 + lk*4 + r;
                    const float o = acc[m][n][r] + bv;
                    const size_t off = (size_t)row * ldC + col;
                    if (isPw) omb[off] = o;
                    else      val_b[off] = f2bf(o);
                }
            }
        }
    }
}

// ---------------------------------------------------------------------------
// K3: fused deformable gather + output projection.
// 256 blocks x 512 thr, 2 blocks/CU. Block = one image row (64 pos) of one n,
// XCD-octile decode (h = xcd*8 + rd) for L2 locality of val row reuse.
// Gather: wave = (g = wave&3, pos-half = wave>>2); 4 lanes x 16 ch per pos;
// each lane loops i=0,1 over two 16-pos sets. Direct global corner loads.
// Pout: wave owns 32 c-rows x 64 cols (no weight duplication across waves).
// ---------------------------------------------------------------------------
__global__ __launch_bounds__(512, 2) void gather_pout(
    const float* __restrict__ om, const u16* __restrict__ val,
    const u16* __restrict__ pout_wb, const float* __restrict__ pout_b,
    float* __restrict__ out)
{
    __shared__ u16 sacc[64][264];
    const int blk = blockIdx.x;                // 0..255
    const int xcd = blk & 7, s = blk >> 3;     // s: 0..31
    const int n = s >> 3, rd = s & 7;
    const int h = xcd * 8 + rd;
    const int l0 = h * 64;
    const int t = threadIdx.x;
    const int wave = t >> 6, lane = t & 63;

    // ---- Phase A: deformable bilinear gather -> sacc ----
    {
        const int g = wave & 3, ph = wave >> 2;
        const int pq = lane >> 2;               // 0..15
        const int cl = (lane & 3) * 16;         // channel base within group
        const u16* valn = val + (size_t)n * L_DIM * 256;
        const u16* vb = valn + g * 64 + cl;
        const float ybase = (float)h - 1.f;

        #pragma unroll
        for (int i = 0; i < 2; ++i) {
            const int pos = ph * 32 + i * 16 + pq;   // 0..63
            const int l = l0 + pos;
            const float* omp = om + ((size_t)n * L_DIM + l) * 112 + g * 27;
            const float xb = (float)pos - 1.f;

            float a[16];
            #pragma unroll
            for (int j = 0; j < 16; ++j) a[j] = 0.f;

            #pragma unroll 3
            for (int p = 0; p < 9; ++p) {
                const float ox = omp[p*3 + 0];
                const float oy = omp[p*3 + 1];
                const float mk = omp[p*3 + 2];
                const float py = ybase + (float)(p / 3) + oy;
                const float px = xb + (float)(p % 3) + ox;
                const float y0 = floorf(py), x0 = floorf(px);
                const float fy = py - y0, fx = px - x0;
                const int iy0 = (int)y0, ix0 = (int)x0;
                const float wy[2] = {mk * (1.f - fy), mk * fy};
                const float wx[2] = {1.f - fx, fx};
                #pragma unroll
                for (int c4 = 0; c4 < 4; ++c4) {
                    const int dy = c4 >> 1, dx = c4 & 1;
                    const int iy = iy0 + dy, ix = ix0 + dx;
                    const bool ok = ((unsigned)iy < 64u) & ((unsigned)ix < 64u);
                    const float wgt = ok ? wy[dy] * wx[dx] : 0.f;
                    const int iyc = min(max(iy, 0), 63);
                    const int ixc = min(max(ix, 0), 63);
                    const u16* lp = vb + (size_t)(iyc * 64 + ixc) * 256;
                    const u16x8 v0 = *(const u16x8*)lp;
                    const u16x8 v1 = *(const u16x8*)(lp + 8);
                    #pragma unroll
                    for (int j = 0; j < 8; ++j) a[j]     = fmaf(wgt, bf2f(v0[j]), a[j]);
                    #pragma unroll
                    for (int j = 0; j < 8; ++j) a[j + 8] = fmaf(wgt, bf2f(v1[j]), a[j + 8]);
                }
            }
            u16x8 o0, o1;
            #pragma unroll
            for (int j = 0; j < 8; ++j) { o0[j] = f2bf(a[j]); o1[j] = f2bf(a[j + 8]); }
            *(u16x8*)(&sacc[pos][g*64 + cl])     = o0;
            *(u16x8*)(&sacc[pos][g*64 + cl + 8]) = o1;
        }
    }
    __syncthreads();

    // ---- Phase B: pout GEMM. Wave owns c-rows [wave*32, wave*32+32). ----
    const int lr = lane & 15, lk = lane >> 4;

    f32x4 acc4[2][4];
    #pragma unroll
    for (int m = 0; m < 2; ++m)
        #pragma unroll
        for (int nn = 0; nn < 4; ++nn) acc4[m][nn] = (f32x4){0.f, 0.f, 0.f, 0.f};

    #pragma unroll
    for (int kt = 0; kt < 8; ++kt) {
        bf16x8 bfr[4];
        #pragma unroll
        for (int nn = 0; nn < 4; ++nn)
            bfr[nn] = *(const bf16x8*)(&sacc[nn*16 + lr][kt*32 + lk*8]);
        #pragma unroll
        for (int m = 0; m < 2; ++m) {
            const bf16x8 af = *(const bf16x8*)(pout_wb +
                (size_t)(wave*32 + m*16 + lr) * K_DIM + kt*32 + lk*8);
            #pragma unroll
            for (int nn = 0; nn < 4; ++nn)
                acc4[m][nn] = __builtin_amdgcn_mfma_f32_16x16x32_bf16(
                    af, bfr[nn], acc4[m][nn], 0, 0, 0);
        }
    }

    float* outn = out + (size_t)n * 256 * L_DIM;
    #pragma unroll
    for (int m = 0; m < 2; ++m) {
        #pragma unroll
        for (int nn = 0; nn < 4; ++nn) {
            const int col = l0 + nn*16 + lr;
            #pragma unroll
            for (int r = 0; r < 4; ++r) {
                const int row = wave*32 + m*16 + lk*4 + r;
                outn[(size_t)row * L_DIM + col] = acc4[m][nn][r] + pout_b[row];
            }
        }
    }
}

// ---------------------------------------------------------------------------
extern "C" void kernel_launch(void* const* d_in, const int* in_sizes, int n_in,
                              void* d_out, int out_size, void* d_ws, size_t ws_size,
                              hipStream_t stream) {
    const float* x      = (const float*)d_in[0];
    const float* dw_w   = (const float*)d_in[1];
    const float* dw_b   = (const float*)d_in[2];
    const float* pw_w   = (const float*)d_in[3];
    const float* pw_b   = (const float*)d_in[4];
    const float* pin_w  = (const float*)d_in[5];
    const float* pin_b  = (const float*)d_in[6];
    const float* pout_w = (const float*)d_in[7];
    const float* pout_b = (const float*)d_in[8];
    float* out = (float*)d_out;

    char* ws = (char*)d_ws;
    u16*   xb_t    = (u16*)ws;                      //  8,388,608
    u16*   dwc_t   = (u16*)(ws + 8388608);          //  8,388,608
    u16*   val_b   = (u16*)(ws + 16777216);         //  8,388,608
    float* omb     = (float*)(ws + 25165824);       //  7,340,032
    u16*   pin_wb  = (u16*)(ws + 32505856);         //    131,072
    u16*   pw_wb   = (u16*)(ws + 32636928);         //     65,536 (128 rows)
    u16*   pout_wb = (u16*)(ws + 32702464);         //    131,072

    // K1: depthwise conv + transpose-cast + weight casts
    prep_kernel<<<dim3(5, 64, NBATCH), 256, 0, stream>>>(
        x, dw_w, dw_b, pin_w, pw_w, pout_w,
        xb_t, dwc_t, pin_wb, pw_wb, pout_wb);

    // K2: val = pin(x) [bf16], om = pw(dwc) [fp32]
    gemm_dual<<<dim3(3, 128), 256, 0, stream>>>(
        xb_t, dwc_t, pin_wb, pw_wb, pin_b, pw_b, val_b, omb);

    // K3: deformable gather + pout projection, 64-pos blocks, octile swizzle
    gather_pout<<<dim3(256), 512, 0, stream>>>(
        omb, val_b, pout_wb, pout_b, out);
}